// Round 17
// baseline (1076.851 us; speedup 1.0000x reference)
//
#include <hip/hip_runtime.h>
#include <math.h>

#define HID 128
#define G3  384
#define BATCH 256
#define SEQ 512
#define NB 16            // batch tile (fallback scan)
#define NBLK (BATCH/NB)
#define NBS 2            // batch tile (fused scan)
#define NBLKS (BATCH/NBS)      // 128 scan blocks
#define NGEMM 1024             // gemm chunks (128 m-rows each)
#define GHP 392          // ghsF row pad (f32)

typedef __bf16 bf16x8 __attribute__((ext_vector_type(8)));
typedef __bf16 bf16x4 __attribute__((ext_vector_type(4)));
typedef float  f32x4  __attribute__((ext_vector_type(4)));

#define LOG2E 1.44269504088896f
#define SC_RZ (-1.44269504088896f)
#define SC_N  (-2.88539008177793f)

__device__ __forceinline__ float sigm(float x) {
    return __builtin_amdgcn_rcpf(1.f + __builtin_amdgcn_exp2f(-LOG2E * x));
}
__device__ __forceinline__ float tanh_fast(float x) {
    float e = __builtin_amdgcn_exp2f(-2.f * LOG2E * x);
    return __builtin_amdgcn_rcpf(1.f + e) * 2.f - 1.f;
}
__device__ __forceinline__ f32x4 mfma16(bf16x8 a, bf16x8 b, f32x4 c) {
    return __builtin_amdgcn_mfma_f32_16x16x32_bf16(a, b, c, 0, 0, 0);
}
__device__ __forceinline__ bf16x8 cvt8(float4 a, float4 b) {
    bf16x8 f;
    f[0] = (__bf16)a.x; f[1] = (__bf16)a.y; f[2] = (__bf16)a.z; f[3] = (__bf16)a.w;
    f[4] = (__bf16)b.x; f[5] = (__bf16)b.y; f[6] = (__bf16)b.z; f[7] = (__bf16)b.w;
    return f;
}
__device__ __forceinline__ bf16x8 cvt8s(float4 a, float4 b, float s) {
    bf16x8 f;
    f[0] = (__bf16)(a.x*s); f[1] = (__bf16)(a.y*s); f[2] = (__bf16)(a.z*s); f[3] = (__bf16)(a.w*s);
    f[4] = (__bf16)(b.x*s); f[5] = (__bf16)(b.y*s); f[6] = (__bf16)(b.z*s); f[7] = (__bf16)(b.w*s);
    return f;
}
__device__ __forceinline__ bf16x4 cvt4(float4 a) {
    bf16x4 f;
    f[0] = (__bf16)a.x; f[1] = (__bf16)a.y; f[2] = (__bf16)a.z; f[3] = (__bf16)a.w;
    return f;
}

// ===========================================================================
// FAST PATH
// ===========================================================================

// ---- fold: Wcbf = bf16(scale*(W_ih@lin_W)), bcA = scale*(W_ih@lin_b+b_ih)
__global__ void fold_bf16_kernel(const float* __restrict__ lin_W,
                                 const float* __restrict__ lin_b,
                                 const float* __restrict__ W_ih,
                                 const float* __restrict__ b_ih,
                                 __bf16* __restrict__ Wcbf,
                                 float* __restrict__ bcA) {
    const int g = blockIdx.x;
    const int d = threadIdx.x;
    const float sc = (g < 2 * HID) ? SC_RZ : SC_N;
    float acc = 0.f;
    #pragma unroll 16
    for (int e = 0; e < HID; ++e) acc += W_ih[g * HID + e] * lin_W[e * HID + d];
    Wcbf[g * HID + d] = (__bf16)(acc * sc);
    if (d == 0) {
        float b = 0.f;
        for (int e = 0; e < HID; ++e) b += W_ih[g * HID + e] * lin_b[e];
        bcA[g] = (b + b_ih[g]) * sc;
    }
}

// ---- fused producer-consumer kernel -------------------------------------
// blockIdx <  NBLKS : scan block (round-15 structure, 299 us measured)
// blockIdx >= NBLKS : GEMM chunk (chunk = blockIdx-NBLKS, 128 m-rows,
//                     ascending s). Completion flagged per 16-chunk group
//                     (= 8 steps) via device-scope atomics; scan gates its
//                     gx prefetch on the group flag (checked once / 8 steps).

// GEMM half-block tile: MT in [0,4) relative to m0h; clamp prefetch at 3.
#define GEMM_TILE4(MT, CUR, NXT)                                              \
  {                                                                           \
    int mtn_ = (MT) + 1; if (mtn_ > 3) mtn_ = 3;                              \
    const float* pxn_ = X + (size_t)(m0h + mtn_ * 16 + col) * HID + lr * 8;   \
    _Pragma("unroll")                                                         \
    for (int kt = 0; kt < 4; ++kt) {                                          \
        NXT[2 * kt]     = *(const float4*)(pxn_ + kt * 32);                   \
        NXT[2 * kt + 1] = *(const float4*)(pxn_ + kt * 32 + 4);               \
    }                                                                         \
    bf16x8 Bx_[4];                                                            \
    _Pragma("unroll")                                                         \
    for (int kt = 0; kt < 4; ++kt) Bx_[kt] = cvt8(CUR[2 * kt], CUR[2 * kt + 1]); \
    const int m_ = m0h + (MT) * 16 + col;                                     \
    _Pragma("unroll")                                                         \
    for (int j = 0; j < 6; ++j) {                                             \
        f32x4 acc_ = vb[j];                                                   \
        acc_ = mfma16(A[j][0], Bx_[0], acc_);                                 \
        acc_ = mfma16(A[j][1], Bx_[1], acc_);                                 \
        acc_ = mfma16(A[j][2], Bx_[2], acc_);                                 \
        acc_ = mfma16(A[j][3], Bx_[3], acc_);                                 \
        float4 o_; o_.x = acc_[0]; o_.y = acc_[1]; o_.z = acc_[2]; o_.w = acc_[3]; \
        *(bf16x4*)(gx + (size_t)m_ * G3 + (w4 * 6 + j) * 16 + lr * 4) = cvt4(o_); \
    }                                                                         \
  }

#define SPLIT_STEP(S, C0, C1, C2, N0, N1, N2)                                 \
  {                                                                           \
    /* phase 1: gh = scaled W_hh @ h (+scaled b_hh via acc init) */           \
    bf16x8 Bh_[4];                                                            \
    _Pragma("unroll")                                                         \
    for (int kt = 0; kt < 4; ++kt)                                            \
        Bh_[kt] = *(const bf16x8*)(hbuf + SW(col, kt * 64 + lr * 16));        \
    f32x4 ar_ = vbr, az_ = vbz, anh_ = vbnh;                                  \
    _Pragma("unroll")                                                         \
    for (int kt = 0; kt < 4; ++kt) {                                          \
        ar_  = mfma16(aW[0][kt], Bh_[kt], ar_);                               \
        az_  = mfma16(aW[1][kt], Bh_[kt], az_);                               \
        anh_ = mfma16(aW[2][kt], Bh_[kt], anh_);                              \
    }                                                                         \
    if (col < NBS) {                                                          \
        float* gp_ = ghsF + col * GHP + w * 16 + lr * 4;                      \
        *(f32x4*)(gp_)       = ar_;                                           \
        *(f32x4*)(gp_ + 128) = az_;                                           \
        *(f32x4*)(gp_ + 256) = anh_;                                          \
    }                                                                         \
    asm volatile("s_waitcnt lgkmcnt(0)" ::: "memory");                        \
    __builtin_amdgcn_s_barrier();                                             \
    /* phase 2 (waves 0-3 only; wave-uniform branch) */                       \
    if (t < 256) {                                                            \
        int sp_ = (S) + 1; if (sp_ > SEQ - 1) sp_ = SEQ - 1;                  \
        /* producer gate: once per 8 steps, wait for gx group (16 chunks). \
           The atomic load's implicit drain removes only OLDER vmem entries \
           -> vmcnt(4) invariant below is preserved. */                       \
        int g_ = sp_ >> 3;                                                    \
        if (g_ != curgrp) {                                                   \
            curgrp = g_;                                                      \
            while (__hip_atomic_load(cnt + g_, __ATOMIC_RELAXED,              \
                                     __HIP_MEMORY_SCOPE_AGENT) < 16u)         \
                __builtin_amdgcn_s_sleep(2);                                  \
            __threadfence();                                                  \
        }                                                                     \
        const __bf16* p_ = gx + (size_t)sp_ * (BATCH * G3) + gxoff;           \
        asm volatile("global_load_ushort %0, %3, off\n\t"                     \
                     "global_load_ushort %1, %3, off offset:256\n\t"          \
                     "global_load_ushort %2, %3, off offset:512"              \
                     : "=&v"(N0), "=&v"(N1), "=&v"(N2) : "v"(p_) : "memory"); \
        float gr_ = ghsF[bi * GHP + ri];                                      \
        float gz_ = ghsF[bi * GHP + 128 + ri];                                \
        float gn_ = ghsF[bi * GHP + 256 + ri];                                \
        asm volatile("s_waitcnt vmcnt(4)" ::: "memory");                      \
        __builtin_amdgcn_sched_barrier(0);                                    \
        float xr_ = __uint_as_float((C0) << 16);                              \
        float xz_ = __uint_as_float((C1) << 16);                              \
        float xn_ = __uint_as_float((C2) << 16);                              \
        float r_ = __builtin_amdgcn_rcpf(1.f + __builtin_amdgcn_exp2f(gr_ + xr_)); \
        float z_ = __builtin_amdgcn_rcpf(1.f + __builtin_amdgcn_exp2f(gz_ + xz_)); \
        float n_ = 2.f * __builtin_amdgcn_rcpf(1.f + __builtin_amdgcn_exp2f(xn_ + r_ * gn_)) - 1.f; \
        float hn_ = n_ + z_ * (hold - n_);                                    \
        hold = hn_;                                                           \
        *(__bf16*)(hbuf + SW(bi, ri * 2)) = (__bf16)hn_;                      \
        out[((size_t)(S) * BATCH + bb + bi) * HID + ri] = hn_;                \
    }                                                                         \
    asm volatile("s_waitcnt lgkmcnt(0)" ::: "memory");                        \
    __builtin_amdgcn_s_barrier();                                             \
  }

__global__ __launch_bounds__(512, 2)
void fused_gemm_scan(const float* __restrict__ X,
                     const __bf16* __restrict__ Wcbf,
                     const float* __restrict__ bcA,
                     __bf16* __restrict__ gx,
                     unsigned* __restrict__ cnt,
                     const float* __restrict__ h0,
                     const float* __restrict__ W_hh,
                     const float* __restrict__ b_hh,
                     float* __restrict__ out) {
    const int t = threadIdx.x;

    if (blockIdx.x >= NBLKS) {
        // ------------------- GEMM producer path ---------------------------
        const int chunk = blockIdx.x - NBLKS;       // 0..1023, ascending s
        const int wg  = t >> 8;                     // 0..1: half (4 m-tiles)
        const int w4  = (t >> 6) & 3;               // wave within half
        const int l   = t & 63;
        const int col = l & 15;
        const int lr  = l >> 4;
        const int m0h = chunk * 128 + wg * 64;

        bf16x8 A[6][4];
        #pragma unroll
        for (int j = 0; j < 6; ++j)
            #pragma unroll
            for (int kt = 0; kt < 4; ++kt)
                A[j][kt] = *(const bf16x8*)(Wcbf +
                    (size_t)((w4 * 6 + j) * 16 + col) * HID + kt * 32 + lr * 8);
        #pragma unroll
        for (int j = 0; j < 6; ++j)
            #pragma unroll
            for (int kt = 0; kt < 4; ++kt)
                asm volatile("" : "+v"(A[j][kt]));

        f32x4 vb[6];
        #pragma unroll
        for (int j = 0; j < 6; ++j)
            vb[j] = *(const f32x4*)(bcA + (w4 * 6 + j) * 16 + lr * 4);

        float4 xe[8], xo[8];
        {
            const float* px = X + (size_t)(m0h + col) * HID + lr * 8;
            #pragma unroll
            for (int kt = 0; kt < 4; ++kt) {
                xe[2 * kt]     = *(const float4*)(px + kt * 32);
                xe[2 * kt + 1] = *(const float4*)(px + kt * 32 + 4);
            }
        }
        GEMM_TILE4(0, xe, xo);
        GEMM_TILE4(1, xo, xe);
        GEMM_TILE4(2, xe, xo);
        GEMM_TILE4(3, xo, xe);

        __syncthreads();                 // drains all waves' stores (vmcnt 0)
        if (t == 0) {
            __threadfence();             // device-visible release
            atomicAdd(&cnt[chunk >> 4], 1u);
        }
        return;
    }

    // ----------------------- scan consumer path ---------------------------
    const int w   = t >> 6;     // 0..7: row tile (16 rows/gate)
    const int l   = t & 63;
    const int col = l & 15;
    const int lr  = l >> 4;
    const int bb  = blockIdx.x * NBS;
    const int bi  = t >> 7;     // 0..1 for t<256 (phase 2)
    const int ri  = t & 127;    // hidden row (phase 2)

    __shared__ __align__(16) unsigned char lds[4096 + NBS * GHP * 4];
    unsigned char* hbuf = lds;                    // [16][128] bf16, swizzled
    float* ghsF = (float*)(lds + 4096);           // [NBS][GHP] f32 gh scratch

    auto SW = [](int b, int off) { return b * 256 + (off ^ ((b & 7) << 4)); };

    bf16x8 aW[3][4];
    #pragma unroll
    for (int g3 = 0; g3 < 3; ++g3) {
        const float s = (g3 < 2) ? SC_RZ : SC_N;
        #pragma unroll
        for (int kt = 0; kt < 4; ++kt) {
            const int row = g3 * HID + w * 16 + col;
            const float* pw = W_hh + row * HID + kt * 32 + lr * 8;
            aW[g3][kt] = cvt8s(*(const float4*)pw, *(const float4*)(pw + 4), s);
        }
    }
    #pragma unroll
    for (int g3 = 0; g3 < 3; ++g3)
        #pragma unroll
        for (int kt = 0; kt < 4; ++kt)
            asm volatile("" : "+v"(aW[g3][kt]));

    f32x4 vbr, vbz, vbnh;
    #pragma unroll
    for (int q = 0; q < 4; ++q) {
        const int g = w * 16 + lr * 4 + q;
        vbr[q]  = b_hh[g] * SC_RZ;
        vbz[q]  = b_hh[HID + g] * SC_RZ;
        vbnh[q] = b_hh[2 * HID + g] * SC_N;
    }

    float hold = 0.f;
    if (t < 256) hold = h0[(size_t)(bb + bi) * HID + ri];
    asm volatile("" :: "v"(hold), "v"(vbr), "v"(vbz), "v"(vbnh));

    const size_t gxoff = (size_t)(bb + bi) * G3 + ri;

    // stage h0 rows 0..1 (t<32) and zero rows 2..15 (t=32..255)
    if (t < 32) {
        const int sb = t >> 4, k8 = (t & 15) * 8;
        const float* ph = h0 + (size_t)(bb + sb) * HID + k8;
        *(bf16x8*)(hbuf + SW(sb, k8 * 2)) =
            cvt8(*(const float4*)ph, *(const float4*)(ph + 4));
    } else if (t < 256) {
        const int sb = t >> 4, k8 = (t & 15) * 8;
        uint4 z = {0u, 0u, 0u, 0u};
        *(uint4*)(hbuf + SW(sb, k8 * 2)) = z;
    }

    int curgrp = 0;
    unsigned c0 = 0, c1 = 0, c2 = 0, n0, n1, n2, dm;
    if (t < 256) {
        // wait for group 0 (steps 0..7) before priming gx[0]
        while (__hip_atomic_load(cnt + 0, __ATOMIC_RELAXED,
                                 __HIP_MEMORY_SCOPE_AGENT) < 16u)
            __builtin_amdgcn_s_sleep(8);
        __threadfence();
        const __bf16* p_ = gx + gxoff;
        asm volatile("global_load_ushort %0, %3, off\n\t"
                     "global_load_ushort %1, %3, off offset:256\n\t"
                     "global_load_ushort %2, %3, off offset:512"
                     : "=&v"(c0), "=&v"(c1), "=&v"(c2) : "v"(p_) : "memory");
        asm volatile("global_load_ushort %0, %1, off"
                     : "=&v"(dm) : "v"(p_) : "memory");
    }
    asm volatile("s_waitcnt lgkmcnt(0)" ::: "memory");
    __builtin_amdgcn_s_barrier();

    for (int s0 = 0; s0 < SEQ; s0 += 2) {
        SPLIT_STEP(s0,     c0, c1, c2, n0, n1, n2);
        SPLIT_STEP(s0 + 1, n0, n1, n2, c0, c1, c2);
    }
    if (t < 256) asm volatile("" :: "v"(dm));
}

// ===========================================================================
// FALLBACK PATH (round-7 kernels, ~439 us) -- used when ws_size is small
// ===========================================================================
__global__ void fold_kernel(const float* __restrict__ lin_W,
                            const float* __restrict__ lin_b,
                            const float* __restrict__ W_ih,
                            const float* __restrict__ b_ih,
                            float* __restrict__ Wc,
                            float* __restrict__ bcA) {
    const int g = blockIdx.x;
    const int d = threadIdx.x;
    float acc = 0.f;
    for (int e = 0; e < HID; ++e) acc += W_ih[g * HID + e] * lin_W[e * HID + d];
    Wc[g * HID + d] = acc;
    if (d == 0) {
        float b = 0.f;
        for (int e = 0; e < HID; ++e) b += W_ih[g * HID + e] * lin_b[e];
        bcA[g] = b + b_ih[g];
    }
}

__global__ __launch_bounds__(512, 2)
void gru_scan_mfma(const float* __restrict__ X,
                   const float* __restrict__ h0,
                   const float* __restrict__ W_hh,
                   const float* __restrict__ b_hh,
                   const float* __restrict__ Wc,
                   const float* __restrict__ bcA,
                   float* __restrict__ out) {
    const int t   = threadIdx.x;
    const int w   = t >> 6;
    const int l   = t & 63;
    const int col = l & 15;
    const int lr  = l >> 4;
    const int bb  = blockIdx.x * NB;

    __shared__ __align__(16) unsigned char lds[16384];
    unsigned char* hA = lds;
    unsigned char* hB = lds + 4096;
    unsigned char* xA = lds + 8192;
    unsigned char* xB = lds + 12288;

    auto SW = [](int b, int off) { return b * 256 + (off ^ ((b & 7) << 4)); };

    bf16x8 aW[3][4], aC[3][4];
    #pragma unroll
    for (int g3 = 0; g3 < 3; ++g3)
        #pragma unroll
        for (int kt = 0; kt < 4; ++kt) {
            const int row = g3 * HID + w * 16 + col;
            const float* pw = W_hh + row * HID + kt * 32 + lr * 8;
            const float* pc = Wc   + row * HID + kt * 32 + lr * 8;
            aW[g3][kt] = cvt8(*(const float4*)pw, *(const float4*)(pw + 4));
            aC[g3][kt] = cvt8(*(const float4*)pc, *(const float4*)(pc + 4));
        }
    #pragma unroll
    for (int g3 = 0; g3 < 3; ++g3)
        #pragma unroll
        for (int kt = 0; kt < 4; ++kt) {
            asm volatile("" : "+v"(aW[g3][kt]));
            asm volatile("" : "+v"(aC[g3][kt]));
        }

    f32x4 vbr, vbz, vbnx, vbnh;
    #pragma unroll
    for (int q = 0; q < 4; ++q) {
        const int g = w * 16 + lr * 4 + q;
        vbr[q]  = bcA[g] + b_hh[g];
        vbz[q]  = bcA[HID + g] + b_hh[HID + g];
        vbnx[q] = bcA[2 * HID + g];
        vbnh[q] = b_hh[2 * HID + g];
    }

    f32x4 hold = *(const f32x4*)(h0 + (size_t)(bb + col) * HID + w * 16 + lr * 4);

    const int sb = t >> 5;
    const int sk = (t & 31) * 4;

    float4 xp, xq;
    if (t < 256) {
        const int hb = t >> 4, hk = (t & 15) * 8;
        const float* ph = h0 + (size_t)(bb + hb) * HID + hk;
        *(bf16x8*)(hA + SW(hb, hk * 2)) =
            cvt8(*(const float4*)ph, *(const float4*)(ph + 4));
    }
    {
        const float* px = X + ((size_t)0 * BATCH + bb + sb) * HID + sk;
        *(bf16x4*)(xA + SW(sb, sk * 2)) = cvt4(*(const float4*)px);
        const float* p1 = X + ((size_t)1 * BATCH + bb + sb) * HID + sk;
        xp = *(const float4*)p1;
    }
    asm volatile("s_waitcnt lgkmcnt(0)" ::: "memory");
    __builtin_amdgcn_s_barrier();

    auto STEP = [&](int s, unsigned char* hR, unsigned char* hW,
                    unsigned char* xR, unsigned char* xW,
                    float4& xc, float4& xn) {
        *(bf16x4*)(xW + SW(sb, sk * 2)) = cvt4(xc);
        {
            int sp = s + 2; if (sp > SEQ - 1) sp = SEQ - 1;
            const float* px = X + ((size_t)sp * BATCH + bb + sb) * HID + sk;
            xn = *(const float4*)px;
        }
        bf16x8 Bh[4], Bx[4];
        #pragma unroll
        for (int kt = 0; kt < 4; ++kt) {
            Bh[kt] = *(const bf16x8*)(hR + SW(col, kt * 64 + lr * 16));
            Bx[kt] = *(const bf16x8*)(xR + SW(col, kt * 64 + lr * 16));
        }
        f32x4 ar = vbr, az = vbz, anh = vbnh, anx = vbnx;
        #pragma unroll
        for (int kt = 0; kt < 4; ++kt) {
            ar  = mfma16(aW[0][kt], Bh[kt], ar);
            ar  = mfma16(aC[0][kt], Bx[kt], ar);
            az  = mfma16(aW[1][kt], Bh[kt], az);
            az  = mfma16(aC[1][kt], Bx[kt], az);
            anh = mfma16(aW[2][kt], Bh[kt], anh);
            anx = mfma16(aC[2][kt], Bx[kt], anx);
        }
        f32x4 hnew;
        #pragma unroll
        for (int q = 0; q < 4; ++q) {
            float r = sigm(ar[q]);
            float z = sigm(az[q]);
            float n = tanh_fast(anx[q] + r * anh[q]);
            hnew[q] = n + z * (hold[q] - n);
        }
        hold = hnew;
        *(bf16x4*)(hW + SW(col, (w * 16 + lr * 4) * 2)) = cvt4(*(float4*)&hnew);
        float4 o; o.x = hnew[0]; o.y = hnew[1]; o.z = hnew[2]; o.w = hnew[3];
        *(float4*)(out + ((size_t)s * BATCH + bb + col) * HID + w * 16 + lr * 4) = o;
        asm volatile("s_waitcnt lgkmcnt(0)" ::: "memory");
        __builtin_amdgcn_s_barrier();
    };

    for (int s0 = 0; s0 < SEQ; s0 += 2) {
        STEP(s0,     hA, hB, xA, xB, xp, xq);
        STEP(s0 + 1, hB, hA, xB, xA, xq, xp);
    }
}

// ---------------------------------------------------------------------------
extern "C" void kernel_launch(void* const* d_in, const int* in_sizes, int n_in,
                              void* d_out, int out_size, void* d_ws, size_t ws_size,
                              hipStream_t stream) {
    const float* X     = (const float*)d_in[0];
    const float* h0    = (const float*)d_in[1];
    const float* lin_W = (const float*)d_in[2];
    const float* lin_b = (const float*)d_in[3];
    const float* W_ih  = (const float*)d_in[4];
    const float* W_hh  = (const float*)d_in[5];
    const float* b_ih  = (const float*)d_in[6];
    const float* b_hh  = (const float*)d_in[7];
    float* out = (float*)d_out;

    const size_t GX_BYTES   = (size_t)SEQ * BATCH * G3 * 2;  // 100663296
    const size_t WCBF_BYTES = (size_t)G3 * HID * 2;          // 98304
    const size_t BCA_BYTES  = (size_t)G3 * 4;                // 1536
    const size_t CNT_BYTES  = 64 * sizeof(unsigned);         // 256

    if (ws_size >= GX_BYTES + WCBF_BYTES + BCA_BYTES + CNT_BYTES) {
        __bf16*   gxp  = (__bf16*)d_ws;
        __bf16*   Wcbf = (__bf16*)((char*)d_ws + GX_BYTES);
        float*    bcA  = (float*)((char*)d_ws + GX_BYTES + WCBF_BYTES);
        unsigned* cnt  = (unsigned*)((char*)d_ws + GX_BYTES + WCBF_BYTES + BCA_BYTES);

        hipMemsetAsync(cnt, 0, CNT_BYTES, stream);
        fold_bf16_kernel<<<G3, HID, 0, stream>>>(lin_W, lin_b, W_ih, b_ih, Wcbf, bcA);
        fused_gemm_scan<<<NBLKS + NGEMM, 512, 0, stream>>>(
            X, Wcbf, bcA, gxp, cnt, h0, W_hh, b_hh, out);
    } else {
        float* Wc  = (float*)d_ws;
        float* bcA = Wc + G3 * HID;
        fold_kernel<<<G3, HID, 0, stream>>>(lin_W, lin_b, W_ih, b_ih, Wc, bcA);
        gru_scan_mfma<<<NBLK, 512, 0, stream>>>(X, h0, W_hh, b_hh, Wc, bcA, out);
    }
}

// Round 18
// 354.000 us; speedup vs baseline: 3.0419x; 3.0419x over previous
//
#include <hip/hip_runtime.h>
#include <math.h>

#define HID 128
#define G3  384
#define BATCH 256
#define SEQ 512
#define NB 16            // batch tile (fallback scan)
#define NBLK (BATCH/NB)
#define NB2 2            // batch tile (split scan)
#define NBLK2 (BATCH/NB2)
#define GHP 392          // ghsF row pad (f32)

typedef __bf16 bf16x8 __attribute__((ext_vector_type(8)));
typedef __bf16 bf16x4 __attribute__((ext_vector_type(4)));
typedef float  f32x4  __attribute__((ext_vector_type(4)));

#define LOG2E 1.44269504088896f
// gate scales folded into weights/biases: r,z: -log2e ; n: -2*log2e
#define SC_RZ (-1.44269504088896f)
#define SC_N  (-2.88539008177793f)

__device__ __forceinline__ float sigm(float x) {
    return __builtin_amdgcn_rcpf(1.f + __builtin_amdgcn_exp2f(-LOG2E * x));
}
__device__ __forceinline__ float tanh_fast(float x) {
    float e = __builtin_amdgcn_exp2f(-2.f * LOG2E * x);
    return __builtin_amdgcn_rcpf(1.f + e) * 2.f - 1.f;
}
__device__ __forceinline__ f32x4 mfma16(bf16x8 a, bf16x8 b, f32x4 c) {
    return __builtin_amdgcn_mfma_f32_16x16x32_bf16(a, b, c, 0, 0, 0);
}
__device__ __forceinline__ bf16x8 cvt8(float4 a, float4 b) {
    bf16x8 f;
    f[0] = (__bf16)a.x; f[1] = (__bf16)a.y; f[2] = (__bf16)a.z; f[3] = (__bf16)a.w;
    f[4] = (__bf16)b.x; f[5] = (__bf16)b.y; f[6] = (__bf16)b.z; f[7] = (__bf16)b.w;
    return f;
}
__device__ __forceinline__ bf16x8 cvt8s(float4 a, float4 b, float s) {
    bf16x8 f;
    f[0] = (__bf16)(a.x*s); f[1] = (__bf16)(a.y*s); f[2] = (__bf16)(a.z*s); f[3] = (__bf16)(a.w*s);
    f[4] = (__bf16)(b.x*s); f[5] = (__bf16)(b.y*s); f[6] = (__bf16)(b.z*s); f[7] = (__bf16)(b.w*s);
    return f;
}
__device__ __forceinline__ bf16x4 cvt4(float4 a) {
    bf16x4 f;
    f[0] = (__bf16)a.x; f[1] = (__bf16)a.y; f[2] = (__bf16)a.z; f[3] = (__bf16)a.w;
    return f;
}

// ===========================================================================
// FAST PATH
// ===========================================================================

// ---- fold: Wcbf = bf16(scale*(W_ih@lin_W)), bcA = scale*(W_ih@lin_b+b_ih)
__global__ void fold_bf16_kernel(const float* __restrict__ lin_W,
                                 const float* __restrict__ lin_b,
                                 const float* __restrict__ W_ih,
                                 const float* __restrict__ b_ih,
                                 __bf16* __restrict__ Wcbf,
                                 float* __restrict__ bcA) {
    const int g = blockIdx.x;
    const int d = threadIdx.x;
    const float sc = (g < 2 * HID) ? SC_RZ : SC_N;
    float acc = 0.f;
    #pragma unroll 16
    for (int e = 0; e < HID; ++e) acc += W_ih[g * HID + e] * lin_W[e * HID + d];
    Wcbf[g * HID + d] = (__bf16)(acc * sc);
    if (d == 0) {
        float b = 0.f;
        for (int e = 0; e < HID; ++e) b += W_ih[g * HID + e] * lin_b[e];
        bcA[g] = (b + b_ih[g]) * sc;
    }
}

// ---- gx GEMM (proven best): resident A (6 g-tiles/wave), streamed X ------
#define GEMM_TILE(MT, CUR, NXT)                                               \
  {                                                                           \
    int mtn_ = (MT) + 1; if (mtn_ > 7) mtn_ = 7;                              \
    const float* pxn_ = X + (size_t)(m0 + mtn_ * 16 + col) * HID + lr * 8;    \
    _Pragma("unroll")                                                         \
    for (int kt = 0; kt < 4; ++kt) {                                          \
        NXT[2 * kt]     = *(const float4*)(pxn_ + kt * 32);                   \
        NXT[2 * kt + 1] = *(const float4*)(pxn_ + kt * 32 + 4);               \
    }                                                                         \
    bf16x8 Bx_[4];                                                            \
    _Pragma("unroll")                                                         \
    for (int kt = 0; kt < 4; ++kt) Bx_[kt] = cvt8(CUR[2 * kt], CUR[2 * kt + 1]); \
    const int m_ = m0 + (MT) * 16 + col;                                      \
    _Pragma("unroll")                                                         \
    for (int j = 0; j < 6; ++j) {                                             \
        f32x4 acc_ = vb[j];                                                   \
        acc_ = mfma16(A[j][0], Bx_[0], acc_);                                 \
        acc_ = mfma16(A[j][1], Bx_[1], acc_);                                 \
        acc_ = mfma16(A[j][2], Bx_[2], acc_);                                 \
        acc_ = mfma16(A[j][3], Bx_[3], acc_);                                 \
        float4 o_; o_.x = acc_[0]; o_.y = acc_[1]; o_.z = acc_[2]; o_.w = acc_[3]; \
        *(bf16x4*)(gx + (size_t)m_ * G3 + (w * 6 + j) * 16 + lr * 4) = cvt4(o_); \
    }                                                                         \
  }

__global__ __launch_bounds__(256, 2)
void gemm_gx2(const float* __restrict__ X,
              const __bf16* __restrict__ Wcbf,
              const float* __restrict__ bcA,
              __bf16* __restrict__ gx) {
    const int t   = threadIdx.x;
    const int w   = t >> 6;
    const int l   = t & 63;
    const int col = l & 15;
    const int lr  = l >> 4;
    const int m0  = blockIdx.x * 128;

    bf16x8 A[6][4];
    #pragma unroll
    for (int j = 0; j < 6; ++j)
        #pragma unroll
        for (int kt = 0; kt < 4; ++kt)
            A[j][kt] = *(const bf16x8*)(Wcbf +
                (size_t)((w * 6 + j) * 16 + col) * HID + kt * 32 + lr * 8);
    #pragma unroll
    for (int j = 0; j < 6; ++j)
        #pragma unroll
        for (int kt = 0; kt < 4; ++kt)
            asm volatile("" : "+v"(A[j][kt]));

    f32x4 vb[6];
    #pragma unroll
    for (int j = 0; j < 6; ++j)
        vb[j] = *(const f32x4*)(bcA + (w * 6 + j) * 16 + lr * 4);

    float4 xe[8], xo[8];
    {
        const float* px = X + (size_t)(m0 + col) * HID + lr * 8;
        #pragma unroll
        for (int kt = 0; kt < 4; ++kt) {
            xe[2 * kt]     = *(const float4*)(px + kt * 32);
            xe[2 * kt + 1] = *(const float4*)(px + kt * 32 + 4);
        }
    }
    for (int mt = 0; mt < 8; mt += 2) {
        GEMM_TILE(mt,     xe, xo);
        GEMM_TILE(mt + 1, xo, xe);
    }
}

// ---- split scan, NB2=2: 128 blocks x 512 thr. Phase 1 = MFMA (gh -> LDS),
// Phase 2 = 1 h-element per thread on waves 0-3 ONLY -> per-SIMD trans issue
// halves vs NB4=4 (each SIMD: one active + one idle wave). 2 barriers/step.
#define SPLIT_STEP(S, C0, C1, C2, N0, N1, N2)                                 \
  {                                                                           \
    /* phase 1: gh = scaled W_hh @ h (+scaled b_hh via acc init) */           \
    bf16x8 Bh_[4];                                                            \
    _Pragma("unroll")                                                         \
    for (int kt = 0; kt < 4; ++kt)                                            \
        Bh_[kt] = *(const bf16x8*)(hbuf + SW(col, kt * 64 + lr * 16));        \
    f32x4 ar_ = vbr, az_ = vbz, anh_ = vbnh;                                  \
    _Pragma("unroll")                                                         \
    for (int kt = 0; kt < 4; ++kt) {                                          \
        ar_  = mfma16(aW[0][kt], Bh_[kt], ar_);                               \
        az_  = mfma16(aW[1][kt], Bh_[kt], az_);                               \
        anh_ = mfma16(aW[2][kt], Bh_[kt], anh_);                              \
    }                                                                         \
    if (col < NB2) {                                                          \
        float* gp_ = ghsF + col * GHP + w * 16 + lr * 4;                      \
        *(f32x4*)(gp_)       = ar_;                                           \
        *(f32x4*)(gp_ + 128) = az_;                                           \
        *(f32x4*)(gp_ + 256) = anh_;                                          \
    }                                                                         \
    asm volatile("s_waitcnt lgkmcnt(0)" ::: "memory");                        \
    __builtin_amdgcn_s_barrier();                                             \
    /* phase 2 (waves 0-3 only; wave-uniform branch) */                       \
    if (t < 256) {                                                            \
        int sp_ = (S) + 1; if (sp_ > SEQ - 1) sp_ = SEQ - 1;                  \
        const __bf16* p_ = gx + (size_t)sp_ * (BATCH * G3) + gxoff;           \
        asm volatile("global_load_ushort %0, %3, off\n\t"                     \
                     "global_load_ushort %1, %3, off offset:256\n\t"          \
                     "global_load_ushort %2, %3, off offset:512"              \
                     : "=&v"(N0), "=&v"(N1), "=&v"(N2) : "v"(p_) : "memory"); \
        float gr_ = ghsF[bi * GHP + ri];                                      \
        float gz_ = ghsF[bi * GHP + 128 + ri];                                \
        float gn_ = ghsF[bi * GHP + 256 + ri];                                \
        /* counted wait: FIFO ... L(S)x3, store(S-1), L(S+1)x3 |vmcnt(4)| */  \
        asm volatile("s_waitcnt vmcnt(4)" ::: "memory");                      \
        __builtin_amdgcn_sched_barrier(0);                                    \
        float xr_ = __uint_as_float((C0) << 16);                              \
        float xz_ = __uint_as_float((C1) << 16);                              \
        float xn_ = __uint_as_float((C2) << 16);                              \
        float r_ = __builtin_amdgcn_rcpf(1.f + __builtin_amdgcn_exp2f(gr_ + xr_)); \
        float z_ = __builtin_amdgcn_rcpf(1.f + __builtin_amdgcn_exp2f(gz_ + xz_)); \
        float n_ = 2.f * __builtin_amdgcn_rcpf(1.f + __builtin_amdgcn_exp2f(xn_ + r_ * gn_)) - 1.f; \
        float hn_ = n_ + z_ * (hold - n_);                                    \
        hold = hn_;                                                           \
        *(__bf16*)(hbuf + SW(bi, ri * 2)) = (__bf16)hn_;                      \
        out[((size_t)(S) * BATCH + bb + bi) * HID + ri] = hn_;                \
    }                                                                         \
    asm volatile("s_waitcnt lgkmcnt(0)" ::: "memory");                        \
    __builtin_amdgcn_s_barrier();                                             \
  }

__global__ __launch_bounds__(512, 2)
void gru_scan_split2(const float* __restrict__ h0,
                     const float* __restrict__ W_hh,
                     const float* __restrict__ b_hh,
                     const __bf16* __restrict__ gx,
                     float* __restrict__ out) {
    const int t   = threadIdx.x;
    const int w   = t >> 6;     // 0..7: row tile (16 rows/gate)
    const int l   = t & 63;
    const int col = l & 15;
    const int lr  = l >> 4;
    const int bb  = blockIdx.x * NB2;
    const int bi  = t >> 7;     // 0..1 for t<256 (phase 2)
    const int ri  = t & 127;    // hidden row (phase 2)

    __shared__ __align__(16) unsigned char lds[4096 + NB2 * GHP * 4];
    unsigned char* hbuf = lds;                    // [16][128] bf16, swizzled
    float* ghsF = (float*)(lds + 4096);           // [NB2][GHP] f32 gh scratch

    auto SW = [](int b, int off) { return b * 256 + (off ^ ((b & 7) << 4)); };

    // resident W_hh A-fragments (48 VGPR), pre-scaled per gate, pinned
    bf16x8 aW[3][4];
    #pragma unroll
    for (int g3 = 0; g3 < 3; ++g3) {
        const float s = (g3 < 2) ? SC_RZ : SC_N;
        #pragma unroll
        for (int kt = 0; kt < 4; ++kt) {
            const int row = g3 * HID + w * 16 + col;
            const float* pw = W_hh + row * HID + kt * 32 + lr * 8;
            aW[g3][kt] = cvt8s(*(const float4*)pw, *(const float4*)(pw + 4), s);
        }
    }
    #pragma unroll
    for (int g3 = 0; g3 < 3; ++g3)
        #pragma unroll
        for (int kt = 0; kt < 4; ++kt)
            asm volatile("" : "+v"(aW[g3][kt]));

    // scaled b_hh as acc initializers (rows w*16 + lr*4 + q)
    f32x4 vbr, vbz, vbnh;
    #pragma unroll
    for (int q = 0; q < 4; ++q) {
        const int g = w * 16 + lr * 4 + q;
        vbr[q]  = b_hh[g] * SC_RZ;
        vbz[q]  = b_hh[HID + g] * SC_RZ;
        vbnh[q] = b_hh[2 * HID + g] * SC_N;
    }

    // per-thread h state (phase-2 element; only meaningful for t<256)
    float hold = 0.f;
    if (t < 256) hold = h0[(size_t)(bb + bi) * HID + ri];
    asm volatile("" :: "v"(hold), "v"(vbr), "v"(vbz), "v"(vbnh));

    const size_t gxoff = (size_t)(bb + bi) * G3 + ri;

    // stage h0 rows 0..1 (t<32) and zero rows 2..15 (t=32..255)
    if (t < 32) {
        const int sb = t >> 4, k8 = (t & 15) * 8;
        const float* ph = h0 + (size_t)(bb + sb) * HID + k8;
        *(bf16x8*)(hbuf + SW(sb, k8 * 2)) =
            cvt8(*(const float4*)ph, *(const float4*)(ph + 4));
    } else if (t < 256) {
        const int sb = t >> 4, k8 = (t & 15) * 8;
        uint4 z = {0u, 0u, 0u, 0u};
        *(uint4*)(hbuf + SW(sb, k8 * 2)) = z;
    }

    // prime: gx[0] (3 ushort asm loads) + 1 dummy (uniform vmcnt math)
    unsigned c0 = 0, c1 = 0, c2 = 0, n0, n1, n2, dm;
    if (t < 256) {
        const __bf16* p_ = gx + gxoff;
        asm volatile("global_load_ushort %0, %3, off\n\t"
                     "global_load_ushort %1, %3, off offset:256\n\t"
                     "global_load_ushort %2, %3, off offset:512"
                     : "=&v"(c0), "=&v"(c1), "=&v"(c2) : "v"(p_) : "memory");
        asm volatile("global_load_ushort %0, %1, off"
                     : "=&v"(dm) : "v"(p_) : "memory");
    }
    asm volatile("s_waitcnt lgkmcnt(0)" ::: "memory");
    __builtin_amdgcn_s_barrier();

    for (int s0 = 0; s0 < SEQ; s0 += 2) {
        SPLIT_STEP(s0,     c0, c1, c2, n0, n1, n2);
        SPLIT_STEP(s0 + 1, n0, n1, n2, c0, c1, c2);
    }
    if (t < 256) asm volatile("" :: "v"(dm));
}

// ===========================================================================
// FALLBACK PATH (round-7 kernels, ~439 us) -- used when ws_size is small
// ===========================================================================
__global__ void fold_kernel(const float* __restrict__ lin_W,
                            const float* __restrict__ lin_b,
                            const float* __restrict__ W_ih,
                            const float* __restrict__ b_ih,
                            float* __restrict__ Wc,
                            float* __restrict__ bcA) {
    const int g = blockIdx.x;
    const int d = threadIdx.x;
    float acc = 0.f;
    for (int e = 0; e < HID; ++e) acc += W_ih[g * HID + e] * lin_W[e * HID + d];
    Wc[g * HID + d] = acc;
    if (d == 0) {
        float b = 0.f;
        for (int e = 0; e < HID; ++e) b += W_ih[g * HID + e] * lin_b[e];
        bcA[g] = b + b_ih[g];
    }
}

__global__ __launch_bounds__(512, 2)
void gru_scan_mfma(const float* __restrict__ X,
                   const float* __restrict__ h0,
                   const float* __restrict__ W_hh,
                   const float* __restrict__ b_hh,
                   const float* __restrict__ Wc,
                   const float* __restrict__ bcA,
                   float* __restrict__ out) {
    const int t   = threadIdx.x;
    const int w   = t >> 6;
    const int l   = t & 63;
    const int col = l & 15;
    const int lr  = l >> 4;
    const int bb  = blockIdx.x * NB;

    __shared__ __align__(16) unsigned char lds[16384];
    unsigned char* hA = lds;
    unsigned char* hB = lds + 4096;
    unsigned char* xA = lds + 8192;
    unsigned char* xB = lds + 12288;

    auto SW = [](int b, int off) { return b * 256 + (off ^ ((b & 7) << 4)); };

    bf16x8 aW[3][4], aC[3][4];
    #pragma unroll
    for (int g3 = 0; g3 < 3; ++g3)
        #pragma unroll
        for (int kt = 0; kt < 4; ++kt) {
            const int row = g3 * HID + w * 16 + col;
            const float* pw = W_hh + row * HID + kt * 32 + lr * 8;
            const float* pc = Wc   + row * HID + kt * 32 + lr * 8;
            aW[g3][kt] = cvt8(*(const float4*)pw, *(const float4*)(pw + 4));
            aC[g3][kt] = cvt8(*(const float4*)pc, *(const float4*)(pc + 4));
        }
    #pragma unroll
    for (int g3 = 0; g3 < 3; ++g3)
        #pragma unroll
        for (int kt = 0; kt < 4; ++kt) {
            asm volatile("" : "+v"(aW[g3][kt]));
            asm volatile("" : "+v"(aC[g3][kt]));
        }

    f32x4 vbr, vbz, vbnx, vbnh;
    #pragma unroll
    for (int q = 0; q < 4; ++q) {
        const int g = w * 16 + lr * 4 + q;
        vbr[q]  = bcA[g] + b_hh[g];
        vbz[q]  = bcA[HID + g] + b_hh[HID + g];
        vbnx[q] = bcA[2 * HID + g];
        vbnh[q] = b_hh[2 * HID + g];
    }

    f32x4 hold = *(const f32x4*)(h0 + (size_t)(bb + col) * HID + w * 16 + lr * 4);

    const int sb = t >> 5;
    const int sk = (t & 31) * 4;

    float4 xp, xq;
    if (t < 256) {
        const int hb = t >> 4, hk = (t & 15) * 8;
        const float* ph = h0 + (size_t)(bb + hb) * HID + hk;
        *(bf16x8*)(hA + SW(hb, hk * 2)) =
            cvt8(*(const float4*)ph, *(const float4*)(ph + 4));
    }
    {
        const float* px = X + ((size_t)0 * BATCH + bb + sb) * HID + sk;
        *(bf16x4*)(xA + SW(sb, sk * 2)) = cvt4(*(const float4*)px);
        const float* p1 = X + ((size_t)1 * BATCH + bb + sb) * HID + sk;
        xp = *(const float4*)p1;
    }
    asm volatile("s_waitcnt lgkmcnt(0)" ::: "memory");
    __builtin_amdgcn_s_barrier();

    auto STEP = [&](int s, unsigned char* hR, unsigned char* hW,
                    unsigned char* xR, unsigned char* xW,
                    float4& xc, float4& xn) {
        *(bf16x4*)(xW + SW(sb, sk * 2)) = cvt4(xc);
        {
            int sp = s + 2; if (sp > SEQ - 1) sp = SEQ - 1;
            const float* px = X + ((size_t)sp * BATCH + bb + sb) * HID + sk;
            xn = *(const float4*)px;
        }
        bf16x8 Bh[4], Bx[4];
        #pragma unroll
        for (int kt = 0; kt < 4; ++kt) {
            Bh[kt] = *(const bf16x8*)(hR + SW(col, kt * 64 + lr * 16));
            Bx[kt] = *(const bf16x8*)(xR + SW(col, kt * 64 + lr * 16));
        }
        f32x4 ar = vbr, az = vbz, anh = vbnh, anx = vbnx;
        #pragma unroll
        for (int kt = 0; kt < 4; ++kt) {
            ar  = mfma16(aW[0][kt], Bh[kt], ar);
            ar  = mfma16(aC[0][kt], Bx[kt], ar);
            az  = mfma16(aW[1][kt], Bh[kt], az);
            az  = mfma16(aC[1][kt], Bx[kt], az);
            anh = mfma16(aW[2][kt], Bh[kt], anh);
            anx = mfma16(aC[2][kt], Bx[kt], anx);
        }
        f32x4 hnew;
        #pragma unroll
        for (int q = 0; q < 4; ++q) {
            float r = sigm(ar[q]);
            float z = sigm(az[q]);
            float n = tanh_fast(anx[q] + r * anh[q]);
            hnew[q] = n + z * (hold[q] - n);
        }
        hold = hnew;
        *(bf16x4*)(hW + SW(col, (w * 16 + lr * 4) * 2)) = cvt4(*(float4*)&hnew);
        float4 o; o.x = hnew[0]; o.y = hnew[1]; o.z = hnew[2]; o.w = hnew[3];
        *(float4*)(out + ((size_t)s * BATCH + bb + col) * HID + w * 16 + lr * 4) = o;
        asm volatile("s_waitcnt lgkmcnt(0)" ::: "memory");
        __builtin_amdgcn_s_barrier();
    };

    for (int s0 = 0; s0 < SEQ; s0 += 2) {
        STEP(s0,     hA, hB, xA, xB, xp, xq);
        STEP(s0 + 1, hB, hA, xB, xA, xq, xp);
    }
}

// ---------------------------------------------------------------------------
extern "C" void kernel_launch(void* const* d_in, const int* in_sizes, int n_in,
                              void* d_out, int out_size, void* d_ws, size_t ws_size,
                              hipStream_t stream) {
    const float* X     = (const float*)d_in[0];
    const float* h0    = (const float*)d_in[1];
    const float* lin_W = (const float*)d_in[2];
    const float* lin_b = (const float*)d_in[3];
    const float* W_ih  = (const float*)d_in[4];
    const float* W_hh  = (const float*)d_in[5];
    const float* b_ih  = (const float*)d_in[6];
    const float* b_hh  = (const float*)d_in[7];
    float* out = (float*)d_out;

    const size_t GX_BYTES   = (size_t)SEQ * BATCH * G3 * 2;  // 100663296
    const size_t WCBF_BYTES = (size_t)G3 * HID * 2;          // 98304
    const size_t BCA_BYTES  = (size_t)G3 * 4;                // 1536

    if (ws_size >= GX_BYTES + WCBF_BYTES + BCA_BYTES) {
        __bf16* gxp  = (__bf16*)d_ws;
        __bf16* Wcbf = (__bf16*)((char*)d_ws + GX_BYTES);
        float*  bcA  = (float*)((char*)d_ws + GX_BYTES + WCBF_BYTES);

        fold_bf16_kernel<<<G3, HID, 0, stream>>>(lin_W, lin_b, W_ih, b_ih, Wcbf, bcA);
        gemm_gx2<<<(SEQ * BATCH) / 128, 256, 0, stream>>>(X, Wcbf, bcA, gxp);
        gru_scan_split2<<<NBLK2, 512, 0, stream>>>(h0, W_hh, b_hh, gxp, out);
    } else {
        float* Wc  = (float*)d_ws;
        float* bcA = Wc + G3 * HID;
        fold_kernel<<<G3, HID, 0, stream>>>(lin_W, lin_b, W_ih, b_ih, Wc, bcA);
        gru_scan_mfma<<<NBLK, 512, 0, stream>>>(X, h0, W_hh, b_hh, Wc, bcA, out);
    }
}